// Round 7
// baseline (198.774 us; speedup 1.0000x reference)
//
#include <hip/hip_runtime.h>
#include <math.h>

#define N_NODES 100000
#define N_EDGES 500000
#define E_HID   64
#define R_HID   32
#define N_RELS  500
#define EPSF    1e-16f
#define D_OUT   224   // 64 (x) + 160 (e_features)

#define SRC_BITS 17
#define SRC_MASK ((1 << SRC_BITS) - 1)   // src < 100000 < 2^17; rel < 500 < 2^15

// native vector types for __builtin_nontemporal_store (HIP float4 class is rejected)
typedef float  nfloat4 __attribute__((ext_vector_type(4)));
typedef float  nfloat2 __attribute__((ext_vector_type(2)));

// fused pre-kernel block ranges (256 threads/block)
#define NSB  ((N_NODES * 16) / 256)          // 6250: 16 lanes/node, float4 cols
#define RSB  ((N_RELS * 8 + 255) / 256)      // 16:   8 lanes/rel,  float4 cols
#define HB   ((N_EDGES + 255) / 256)         // 1954: histogram
#define PRE_GRID (NSB + RSB + HB)

#define SCAN_B  512
#define SCAN_NB ((N_NODES + SCAN_B - 1) / SCAN_B)   // 196

__device__ __forceinline__ float dot4(float4 a, float4 b) {
    return a.x * b.x + a.y * b.y + a.z * b.z + a.w * b.w;
}
__device__ __forceinline__ float4 axpy4(float s, float4 a, float4 acc) {
    acc.x += s * a.x; acc.y += s * a.y; acc.z += s * a.z; acc.w += s * a.w;
    return acc;
}

// --- Kernel 1 (fused): source-node scores + rel scores + dest histogram.
// NOTE: the destination-score term x[ei]·w[0:64] cancels in the segment
// softmax (constant shift per segment) -> never computed.
__global__ void fused_pre_kernel(const float* __restrict__ x,
                                 const float* __restrict__ rel_emb,
                                 const float* __restrict__ ww,
                                 const int* __restrict__ ei,
                                 float* __restrict__ s_j,
                                 float* __restrict__ s_r,
                                 int* __restrict__ count) {
    int b = blockIdx.x;
    if (b < NSB) {
        // s_j[n]=x[n]·w[96:160]; 16 lanes/node, float4
        int t    = b * 256 + threadIdx.x;
        int node = t >> 4, sub = t & 15;
        float4 v  = *(const float4*)&x[node * E_HID + sub * 4];
        float4 wb = *(const float4*)&ww[96 + sub * 4];
        float c = dot4(v, wb);
        #pragma unroll
        for (int off = 8; off > 0; off >>= 1) c += __shfl_down(c, off, 16);
        if (sub == 0) s_j[node] = c;
    } else if (b < NSB + RSB) {
        // s_r[r]=rel_emb[r]·w[64:96]; 8 lanes/rel, float4
        int t   = (b - NSB) * 256 + threadIdx.x;
        int r   = t >> 3, sub = t & 7;
        if (r >= N_RELS) return;
        float4 v  = *(const float4*)&rel_emb[r * R_HID + sub * 4];
        float4 wr = *(const float4*)&ww[64 + sub * 4];
        float a = dot4(v, wr);
        #pragma unroll
        for (int off = 4; off > 0; off >>= 1) a += __shfl_down(a, off, 8);
        if (sub == 0) s_r[r] = a;
    } else {
        int e = (b - NSB - RSB) * 256 + threadIdx.x;
        if (e < N_EDGES) atomicAdd(&count[ei[e]], 1);
    }
}

// --- Kernel 2: one-dispatch scan — block prefix + global-cursor atomic.
// Segment ORDER is arbitrary (only relabels pack slots) -> no hierarchy needed.
__global__ void scan_kernel(const int* __restrict__ count,
                            int* __restrict__ starts,
                            int* __restrict__ gcursor) {
    __shared__ int lds[SCAN_B];
    __shared__ int base_s;
    int tid = threadIdx.x;
    int gid = blockIdx.x * SCAN_B + tid;
    int v = (gid < N_NODES) ? count[gid] : 0;
    lds[tid] = v;
    __syncthreads();
    #pragma unroll
    for (int off = 1; off < SCAN_B; off <<= 1) {
        int t = (tid >= off) ? lds[tid - off] : 0;
        __syncthreads();
        lds[tid] += t;
        __syncthreads();
    }
    if (tid == SCAN_B - 1) base_s = atomicAdd(gcursor, lds[SCAN_B - 1]);
    __syncthreads();
    if (gid < N_NODES) starts[gid] = base_s + lds[tid] - v;   // exclusive
}

// --- Kernel 3: place packed payload {src|rel<<17, exp(sr+sj)} into CSR slots.
// Post-increments starts[] (afterwards starts[d] == segment end).
// Only TWO gathers per edge: s_j[src] (400KB, L2) and s_r[r] (2KB, L1).
__global__ void place_kernel(const int* __restrict__ ei,
                             const int* __restrict__ ej,
                             const int* __restrict__ rel,
                             const float* __restrict__ s_j,
                             const float* __restrict__ s_r,
                             int* __restrict__ starts,
                             int2* __restrict__ pack) {
    int e = blockIdx.x * blockDim.x + threadIdx.x;
    if (e >= N_EDGES) return;
    int d   = ei[e];
    int src = ej[e];
    int r   = rel[e];
    float se = __expf(s_r[r] + s_j[src]);   // |att| ~0.5 std: exp overflow-safe
    int pos = atomicAdd(&starts[d], 1);
    pack[pos] = make_int2(src | (r << SRC_BITS), __float_as_int(se));
}

// --- Kernel 4: aggregate. 16 lanes per node (4 nodes/wave), float4 gathers,
// x4 edge unroll. Out is written with NON-TEMPORAL stores so the 90MB
// write-once stream doesn't evict the x gather working set from L2.
__global__ void node_aggregate_kernel(const int2* __restrict__ pack,
                                      const int* __restrict__ starts_end,
                                      const int* __restrict__ count,
                                      const float* __restrict__ x,
                                      const float* __restrict__ rel_emb,
                                      float* __restrict__ out) {
    int t    = blockIdx.x * blockDim.x + threadIdx.x;
    int node = t >> 4;
    int sub  = t & 15;
    if (node >= N_NODES) return;
    int cnt = count[node];
    int end = starts_end[node];
    int beg = end - cnt;
    float S = 0.0f;
    float4 accx = make_float4(0.f, 0.f, 0.f, 0.f);
    float2 accr = make_float2(0.f, 0.f);
    int k = 0;
    for (; k + 4 <= cnt; k += 4) {
        int2 p0 = pack[beg + k + 0];
        int2 p1 = pack[beg + k + 1];
        int2 p2 = pack[beg + k + 2];
        int2 p3 = pack[beg + k + 3];
        int s0 = p0.x & SRC_MASK, r0 = (unsigned)p0.x >> SRC_BITS;
        int s1 = p1.x & SRC_MASK, r1 = (unsigned)p1.x >> SRC_BITS;
        int s2 = p2.x & SRC_MASK, r2 = (unsigned)p2.x >> SRC_BITS;
        int s3 = p3.x & SRC_MASK, r3 = (unsigned)p3.x >> SRC_BITS;
        float4 x0 = *(const float4*)&x[s0 * E_HID + sub * 4];
        float4 x1 = *(const float4*)&x[s1 * E_HID + sub * 4];
        float4 x2 = *(const float4*)&x[s2 * E_HID + sub * 4];
        float4 x3 = *(const float4*)&x[s3 * E_HID + sub * 4];
        float2 e0 = *(const float2*)&rel_emb[r0 * R_HID + sub * 2];
        float2 e1 = *(const float2*)&rel_emb[r1 * R_HID + sub * 2];
        float2 e2 = *(const float2*)&rel_emb[r2 * R_HID + sub * 2];
        float2 e3 = *(const float2*)&rel_emb[r3 * R_HID + sub * 2];
        float se0 = __int_as_float(p0.y), se1 = __int_as_float(p1.y);
        float se2 = __int_as_float(p2.y), se3 = __int_as_float(p3.y);
        S += (se0 + se1) + (se2 + se3);
        accx = axpy4(se0, x0, accx); accx = axpy4(se1, x1, accx);
        accx = axpy4(se2, x2, accx); accx = axpy4(se3, x3, accx);
        accr.x += se0 * e0.x + se1 * e1.x + se2 * e2.x + se3 * e3.x;
        accr.y += se0 * e0.y + se1 * e1.y + se2 * e2.y + se3 * e3.y;
    }
    for (; k < cnt; k++) {
        int2 p = pack[beg + k];
        int s = p.x & SRC_MASK, r = (unsigned)p.x >> SRC_BITS;
        float se = __int_as_float(p.y);
        float4 xv = *(const float4*)&x[s * E_HID + sub * 4];
        float2 ev = *(const float2*)&rel_emb[r * R_HID + sub * 2];
        S += se;
        accx = axpy4(se, xv, accx);
        accr.x += se * ev.x;
        accr.y += se * ev.y;
    }
    float wv = 1.0f / (S + EPSF);
    float alpha = S * wv;
    float4 xv = *(const float4*)&x[node * E_HID + sub * 4];
    float* o = out + (size_t)node * D_OUT;

    nfloat4 v0 = {xv.x, xv.y, xv.z, xv.w};
    __builtin_nontemporal_store(v0, (nfloat4*)&o[sub * 4]);          // cols 0:64
    nfloat4 v1 = {fmaxf(alpha * xv.x, 0.f), fmaxf(alpha * xv.y, 0.f),
                  fmaxf(alpha * xv.z, 0.f), fmaxf(alpha * xv.w, 0.f)};
    __builtin_nontemporal_store(v1, (nfloat4*)&o[64 + sub * 4]);     // cols 64:128
    nfloat2 v2 = {fmaxf(accr.x * wv, 0.f), fmaxf(accr.y * wv, 0.f)};
    __builtin_nontemporal_store(v2, (nfloat2*)&o[128 + sub * 2]);    // cols 128:160
    nfloat4 v3 = {fmaxf(accx.x * wv, 0.f), fmaxf(accx.y * wv, 0.f),
                  fmaxf(accx.z * wv, 0.f), fmaxf(accx.w * wv, 0.f)};
    __builtin_nontemporal_store(v3, (nfloat4*)&o[160 + sub * 4]);    // cols 160:224
}

extern "C" void kernel_launch(void* const* d_in, const int* in_sizes, int n_in,
                              void* d_out, int out_size, void* d_ws, size_t ws_size,
                              hipStream_t stream) {
    const float* x        = (const float*)d_in[0];               // [N, 64]
    const int*   edge_all = (const int*)  d_in[1];               // [2, E] flat
    const int*   rel      = (const int*)  d_in[2];               // [E]
    const float* rel_emb  = (const float*)d_in[3];               // [500, 32]
    const float* ww       = (const float*)d_in[4];               // [160]
    float*       out      = (float*)d_out;                       // [N, 224]

    const int* ei = edge_all;            // destinations (group index)
    const int* ej = edge_all + N_EDGES;  // sources

    // workspace: pack[E] (int2, 4MB) | s_j[N] | s_r[512] |
    //            count[N] | gcursor | starts[N]
    int2*  pack    = (int2*)d_ws;
    float* s_j     = (float*)(pack + N_EDGES);
    float* s_r     = s_j + N_NODES;
    int*   count   = (int*)(s_r + 512);
    int*   gcursor = count + N_NODES;
    int*   starts  = gcursor + 1;

    // zero count + gcursor in one memset
    (void)hipMemsetAsync(count, 0, (size_t)(N_NODES + 1) * sizeof(int), stream);

    fused_pre_kernel<<<PRE_GRID, 256, 0, stream>>>(x, rel_emb, ww, ei,
                                                   s_j, s_r, count);
    scan_kernel<<<SCAN_NB, SCAN_B, 0, stream>>>(count, starts, gcursor);
    place_kernel<<<(N_EDGES + 255) / 256, 256, 0, stream>>>(ei, ej, rel,
                                                            s_j, s_r,
                                                            starts, pack);
    node_aggregate_kernel<<<(N_NODES * 16) / 256, 256, 0, stream>>>(
        pack, starts, count, x, rel_emb, out);
}